// Round 1
// baseline (268.051 us; speedup 1.0000x reference)
//
#include <hip/hip_runtime.h>

// Problem constants: B=16, S=2048, D=1024, P=8192, R=16, NL=64, span<=31
#define S_LEN      2048
#define D_DIM      1024
#define R_DIM      16
#define OUT_STRIDE 2064          // 2*D + R
#define NBUCK      8192          // (B*S)>>2 coarse sort buckets (32 KB LDS hist)
#define BPT        8             // buckets per thread in the scan (NBUCK/1024)
#define GROUP      4             // sorted jobs per gather group

// ---------------------------------------------------------------------------
// Fused counting sort of the 2P span-jobs by coarse start bucket
// ((b*S + s) >> 2). One workgroup, everything in LDS: zero + histogram +
// scan + scatter in a single dispatch (replaces 4 serialized kernels).
// Coarse key costs <=3 rows of extra window per group but quarters the
// histogram so it fits in 32 KB LDS.
__global__ __launch_bounds__(1024) void sort_jobs(
    const int* __restrict__ bidx, const int* __restrict__ e1s,
    const int* __restrict__ e2s, int* __restrict__ sorted, int njobs)
{
    __shared__ int hist[NBUCK];   // 32 KB
    __shared__ int part[1024];    // 4 KB
    const int t = threadIdx.x;

#pragma unroll
    for (int i = 0; i < BPT; ++i) hist[t * BPT + i] = 0;
    __syncthreads();

    // histogram (LDS atomics)
    for (int j = t; j < njobs; j += 1024) {
        const int p = j >> 1;
        const int s = (j & 1) ? e2s[p] : e1s[p];
        atomicAdd(&hist[(bidx[p] * S_LEN + s) >> 2], 1);
    }
    __syncthreads();

    // exclusive scan: 8 buckets/thread serial + Hillis-Steele over 1024 partials
    int v[BPT];
    int sum = 0;
#pragma unroll
    for (int i = 0; i < BPT; ++i) { v[i] = hist[t * BPT + i]; sum += v[i]; }
    part[t] = sum;
    __syncthreads();
    for (int off = 1; off < 1024; off <<= 1) {
        int x = (t >= off) ? part[t - off] : 0;
        __syncthreads();
        part[t] += x;
        __syncthreads();
    }
    int run = (t == 0) ? 0 : part[t - 1];
#pragma unroll
    for (int i = 0; i < BPT; ++i) { int c = v[i]; hist[t * BPT + i] = run; run += c; }
    __syncthreads();

    // scatter (LDS cursor atomics)
    for (int j = t; j < njobs; j += 1024) {
        const int p = j >> 1;
        const int s = (j & 1) ? e2s[p] : e1s[p];
        const int pos = atomicAdd(&hist[(bidx[p] * S_LEN + s) >> 2], 1);
        sorted[pos] = j;
    }
}

// ---------------------------------------------------------------------------
// Grouped gather v4: GROUP=4 (was 8) so acc[4]+cur[4]+nxt[4] = 48 data VGPRs
// fits in the register file WITHOUT the compiler collapsing the 4-row
// double-buffered prefetch (v3 needed 64 data regs, got squeezed to 48 total
// -> pipeline destroyed -> latency-bound at 2.4 TB/s). Grid doubles to 8192
// blocks for finer load balance; 128 threads x 4 cols = 512-col slice,
// 2 slices per group. Branch-free weighted accumulation, clamped addresses
// instead of a tail loop (out-of-window rows get weight 0).
__global__ __launch_bounds__(128) void gather_g4(
    const float* __restrict__ tok,     // [B*S, D] fp32
    const int*   __restrict__ sorted,  // [2P] sorted job ids
    const int*   __restrict__ bidx,
    const int*   __restrict__ e1s, const int* __restrict__ e1e,
    const int*   __restrict__ e2s, const int* __restrict__ e2e,
    const int*   __restrict__ ridx,
    const float* __restrict__ rtab,    // [NL, R]
    float*       __restrict__ out)     // [P, 2D+R]
{
    const int blk = blockIdx.x;
    // XCD swizzle: give each XCD a CONTIGUOUS range of work units so its L2
    // sees a sliding row window over the sorted groups.
    const int w  = (blk & 7) * (gridDim.x >> 3) + (blk >> 3);
    const int g  = w >> 1;            // job group (4 sorted jobs)
    const int ch = w & 1;             // column half: cols [ch*512, ch*512+512)
    const int t  = threadIdx.x;       // 128 threads x 4 cols = 512 cols

    int   jp[GROUP], jh[GROUP], js[GROUP], je[GROUP];
    float jw[GROUP];
    int mins = 0x7fffffff, maxe = 0;
#pragma unroll
    for (int i = 0; i < GROUP; ++i) {
        const int id = __builtin_amdgcn_readfirstlane(sorted[g * GROUP + i]);
        const int p  = id >> 1;
        const int h  = id & 1;
        const int b  = __builtin_amdgcn_readfirstlane(bidx[p]);
        const int s  = __builtin_amdgcn_readfirstlane(h ? e2s[p] : e1s[p]);
        const int e  = __builtin_amdgcn_readfirstlane(h ? e2e[p] : e1e[p]);
        jp[i] = p; jh[i] = h;
        js[i] = b * S_LEN + s;
        je[i] = b * S_LEN + e;
        jw[i] = 1.0f / (float)(e - s);
        mins  = min(mins, js[i]);
        maxe  = max(maxe, je[i]);
    }

    float4 acc[GROUP];
#pragma unroll
    for (int i = 0; i < GROUP; ++i) acc[i] = make_float4(0.f, 0.f, 0.f, 0.f);

    // row stride = D/4 = 256 float4; this block's slice starts at ch*128 + t
    const float4* base = reinterpret_cast<const float4*>(tok) +
                         (size_t)mins * (D_DIM / 4) + ch * 128 + t;
    const int nrows = maxe - mins;          // >= 1 always
    const int rmax  = nrows - 1;
    const int niter = (nrows + 3) >> 2;

    float4 cur[4];
#pragma unroll
    for (int k = 0; k < 4; ++k)
        cur[k] = base[(size_t)min(k, rmax) * (D_DIM / 4)];

    for (int it = 0; it < niter; ++it) {
        const int r0 = it * 4;
        float4 nxt[4];                      // prefetch next 4 rows (clamped)
#pragma unroll
        for (int k = 0; k < 4; ++k)
            nxt[k] = base[(size_t)min(r0 + 4 + k, rmax) * (D_DIM / 4)];

        const int gr = mins + r0;           // global row of cur[0]
#pragma unroll
        for (int i = 0; i < GROUP; ++i) {   // weights: wave-uniform scalar sel
            const float w0 = (gr + 0 >= js[i] && gr + 0 < je[i]) ? jw[i] : 0.f;
            const float w1 = (gr + 1 >= js[i] && gr + 1 < je[i]) ? jw[i] : 0.f;
            const float w2 = (gr + 2 >= js[i] && gr + 2 < je[i]) ? jw[i] : 0.f;
            const float w3 = (gr + 3 >= js[i] && gr + 3 < je[i]) ? jw[i] : 0.f;
            acc[i].x += cur[0].x * w0 + cur[1].x * w1 + cur[2].x * w2 + cur[3].x * w3;
            acc[i].y += cur[0].y * w0 + cur[1].y * w1 + cur[2].y * w2 + cur[3].y * w3;
            acc[i].z += cur[0].z * w0 + cur[1].z * w1 + cur[2].z * w2 + cur[3].z * w3;
            acc[i].w += cur[0].w * w0 + cur[1].w * w1 + cur[2].w * w2 + cur[3].w * w3;
        }
#pragma unroll
        for (int k = 0; k < 4; ++k) cur[k] = nxt[k];
    }

#pragma unroll
    for (int i = 0; i < GROUP; ++i) {
        float* dst = out + (size_t)jp[i] * OUT_STRIDE + jh[i] * D_DIM +
                     ch * 512 + t * 4;
        *reinterpret_cast<float4*>(dst) = acc[i];
        if (ch == 0 && jh[i] == 0 && t < 4) {   // rel row once per pair
            const float4 rv = *reinterpret_cast<const float4*>(
                rtab + ridx[jp[i]] * R_DIM + t * 4);
            *reinterpret_cast<float4*>(
                out + (size_t)jp[i] * OUT_STRIDE + 2 * D_DIM + t * 4) = rv;
        }
    }
}

// ---------------------------------------------------------------------------
extern "C" void kernel_launch(void* const* d_in, const int* in_sizes, int n_in,
                              void* d_out, int out_size, void* d_ws, size_t ws_size,
                              hipStream_t stream) {
    const float* tok  = (const float*)d_in[0];
    const int*   bidx = (const int*)d_in[1];
    const int*   e1s  = (const int*)d_in[2];
    const int*   e1e  = (const int*)d_in[3];
    const int*   e2s  = (const int*)d_in[4];
    const int*   e2e  = (const int*)d_in[5];
    const int*   ridx = (const int*)d_in[6];
    const float* rtab = (const float*)d_in[7];
    float*       out  = (float*)d_out;

    const int P     = in_sizes[1];   // 8192
    const int njobs = 2 * P;         // 16384

    int* sorted = (int*)d_ws;        // njobs ints

    sort_jobs<<<1, 1024, 0, stream>>>(bidx, e1s, e2s, sorted, njobs);

    const int nblocks = (njobs / GROUP) * 2;        // 2 col-slices per group
    gather_g4<<<nblocks, 128, 0, stream>>>(
        tok, sorted, bidx, e1s, e1e, e2s, e2e, ridx, rtab, out);
}